// Round 12
// baseline (589.232 us; speedup 1.0000x reference)
//
#include <hip/hip_runtime.h>
#include <cmath>

#define CDIV(a,b) (((a)+(b)-1)/(b))

typedef unsigned short bf16_t;
using short8 = __attribute__((ext_vector_type(8))) short;
using f32x4  = __attribute__((ext_vector_type(4))) float;
using u16x4  = __attribute__((ext_vector_type(4))) unsigned short;
using u16x8  = __attribute__((ext_vector_type(8))) unsigned short;

__device__ __forceinline__ float bf2f(unsigned short b) {
    unsigned u = ((unsigned)b) << 16;
    float f;
    __builtin_memcpy(&f, &u, 4);
    return f;
}
__device__ __forceinline__ unsigned short f2bf(float f) {
    unsigned u;
    __builtin_memcpy(&u, &f, 4);
    u = (u + 0x7FFFu + ((u >> 16) & 1u)) >> 16;
    return (unsigned short)u;
}

// ---------------- edge-index width detection ----------------
__global__ void k_detect(const int* __restrict__ ei, int* __restrict__ flag) {
    int t = threadIdx.x;  // 64 threads
    unsigned v = (unsigned)ei[2 * t + 1];
    unsigned long long m = __ballot(v != 0u);
    if (t == 0) *flag = (m == 0ULL) ? 1 : 0;  // 1 => int64 layout
}

__device__ __forceinline__ int edge_src(const int* ei, int E, int f, int i) {
    return f ? ei[2 * (size_t)i] : ei[i];
}
__device__ __forceinline__ int edge_dst(const int* ei, int E, int f, int i) {
    return f ? ei[2 * ((size_t)E + (size_t)i)] : ei[(size_t)E + (size_t)i];
}

// ---------------- CSR build: two-phase, XCD-confined -------------------------
// Phase A: partition edges into 8 dst-range buckets (temp, (src,dst) pairs).
// Phase B: blocks pick bucket blockIdx&7 (= XCD under round-robin dispatch),
// so each bucket's cnt/cur/csr slices stay in ONE XCD's L2.

__global__ __launch_bounds__(256) void k_binA(
        const int* __restrict__ ei, int E, const int* __restrict__ flag,
        int NB8, int CAP, int* __restrict__ gcur, int2* __restrict__ temp, int N) {
    __shared__ int hcnt[8], hbase[8];
    int t = threadIdx.x;
    if (t < 8) hcnt[t] = 0;
    __syncthreads();
    int base = blockIdx.x * 1024;
    int f = *flag;
    int bk[4], rk[4], sv[4], dv[4];
#pragma unroll
    for (int j = 0; j < 4; j++) {
        int i = base + j * 256 + t;
        bk[j] = -1;
        if (i < E) {
            int s = edge_src(ei, E, f, i);
            int d = edge_dst(ei, E, f, i);
            if ((unsigned)d < (unsigned)N && (unsigned)s < (unsigned)N) {
                int b = d / NB8;
                bk[j] = b; sv[j] = s; dv[j] = d;
                rk[j] = atomicAdd(&hcnt[b], 1);
            }
        }
    }
    __syncthreads();
    if (t < 8) hbase[t] = atomicAdd(&gcur[t], hcnt[t]);
    __syncthreads();
#pragma unroll
    for (int j = 0; j < 4; j++) {
        if (bk[j] >= 0) {
            int pos = hbase[bk[j]] + rk[j];
            if (pos < CAP) temp[(size_t)bk[j] * CAP + pos] = make_int2(sv[j], dv[j]);
        }
    }
}

__global__ __launch_bounds__(256) void k_hist2(
        const int2* __restrict__ temp, const int* __restrict__ gcur, int CAP,
        int* __restrict__ cnt) {
    int r = blockIdx.x & 7;
    int nb = gridDim.x >> 3;
    int lb = blockIdx.x >> 3;
    int n = min(gcur[r], CAP);
    for (int i = lb * 256 + threadIdx.x; i < n; i += nb * 256)
        atomicAdd(&cnt[temp[(size_t)r * CAP + i].y], 1);
}

__global__ __launch_bounds__(256) void k_fillB(
        const int2* __restrict__ temp, const int* __restrict__ gcur, int CAP,
        int* __restrict__ cur, int* __restrict__ csr) {
    int r = blockIdx.x & 7;
    int nb = gridDim.x >> 3;
    int lb = blockIdx.x >> 3;
    int n = min(gcur[r], CAP);
    for (int i = lb * 256 + threadIdx.x; i < n; i += nb * 256) {
        int2 e = temp[(size_t)r * CAP + i];
        int p = atomicAdd(&cur[e.y], 1);
        csr[p] = e.x;
    }
}

// block-sum over 1024 entries of cnt
__global__ void k_blockred(const int* __restrict__ cnt, int* __restrict__ bsum, int total) {
    __shared__ int sd[256];
    int b = blockIdx.x, t = threadIdx.x;
    int base = b * 1024 + t * 4;
    int s = 0;
#pragma unroll
    for (int i = 0; i < 4; i++) { int idx = base + i; if (idx < total) s += cnt[idx]; }
    sd[t] = s; __syncthreads();
    for (int off = 128; off > 0; off >>= 1) { if (t < off) sd[t] += sd[t + off]; __syncthreads(); }
    if (t == 0) bsum[b] = sd[0];
}

__global__ void k_scanpartials(int* bsum, int nb) {
    __shared__ int sd[256];
    int t = threadIdx.x;
    int v = (t < nb) ? bsum[t] : 0;
    sd[t] = v; __syncthreads();
    for (int off = 1; off < 256; off <<= 1) {
        int y = (t >= off) ? sd[t - off] : 0;
        __syncthreads();
        sd[t] += y;
        __syncthreads();
    }
    if (t < nb) bsum[t] = sd[t] - v;   // exclusive
}

__global__ void k_scanwrite(const int* __restrict__ cnt, const int* __restrict__ bsum,
                            int* __restrict__ rowptr, int* __restrict__ cur,
                            float* __restrict__ dis, int total, int N) {
    __shared__ int sd[256];
    int b = blockIdx.x, t = threadIdx.x;
    int base = b * 1024 + t * 4;
    int v[4]; int s = 0;
#pragma unroll
    for (int i = 0; i < 4; i++) { int idx = base + i; v[i] = (idx < total) ? cnt[idx] : 0; s += v[i]; }
    sd[t] = s; __syncthreads();
    for (int off = 1; off < 256; off <<= 1) {
        int y = (t >= off) ? sd[t - off] : 0;
        __syncthreads();
        sd[t] += y;
        __syncthreads();
    }
    int pre = bsum[b] + sd[t] - s;
#pragma unroll
    for (int i = 0; i < 4; i++) {
        int idx = base + i;
        if (idx < total) {
            rowptr[idx] = pre;
            if (idx < N) { cur[idx] = pre; dis[idx] = rsqrtf((float)v[i] + 1.0f); }
            pre += v[i];
        }
    }
}

// ---------------- pad/convert x: [N,40] fp32 -> [N,64] bf16 (zero-padded) ----

__global__ __launch_bounds__(256) void k_pad(const float* __restrict__ x,
                                             bf16_t* __restrict__ xb, int N) {
    int i = blockIdx.x * 256 + threadIdx.x;
    int row = i >> 6, col = i & 63;
    if (row >= N) return;
    float v = (col < 40) ? x[(size_t)row * 40 + col] : 0.f;
    xb[(size_t)row * 64 + col] = f2bf(v);
}

// ---------------- weight pre-convert: fp32 [M,KW] -> bf16 [M,KP] ------------

struct WcSeg { const float* src; bf16_t* dst; int M, KW, KP, nchunk; };

__global__ __launch_bounds__(256) void k_wconv(WcSeg s0, WcSeg s1, WcSeg s2,
                                               WcSeg s3, WcSeg s4, int total) {
    int i = blockIdx.x * 256 + threadIdx.x;
    if (i >= total) return;
    WcSeg s;
    if (i < s0.nchunk) s = s0;
    else if ((i -= s0.nchunk) < s1.nchunk) s = s1;
    else if ((i -= s1.nchunk) < s2.nchunk) s = s2;
    else if ((i -= s2.nchunk) < s3.nchunk) s = s3;
    else { i -= s3.nchunk; s = s4; }
    int cpr = s.KP >> 3;                // chunks per row
    int row = i / cpr, kk = (i % cpr) << 3;
    short8 v = {};
    if (kk < s.KW) {
        const float4* p = (const float4*)(s.src + (size_t)row * s.KW + kk);
        float4 a = p[0], b = p[1];
        v[0] = (short)f2bf(a.x); v[1] = (short)f2bf(a.y);
        v[2] = (short)f2bf(a.z); v[3] = (short)f2bf(a.w);
        v[4] = (short)f2bf(b.x); v[5] = (short)f2bf(b.y);
        v[6] = (short)f2bf(b.z); v[7] = (short)f2bf(b.w);
    }
    *(short8*)(s.dst + (size_t)row * s.KP + kk) = v;
}

// ---------------- MFMA GEMM: C[i][j] = sum_k A[i][k] * Wb[j][k] --------------
// A: [N,K] bf16, Wb: [M,K] bf16. K mult of 64, M of 128. 128x128 tile,
// 4 waves (2x2), mfma_f32_16x16x32_bf16, BK=64, XOR-swizzled LDS.
// Grid: x = M-tile (fastest), y = N-tile, z = K-segment when SPLIT.

template <bool CBF, bool BIAS, int ACT, bool SPLIT>
__global__ __launch_bounds__(256) void gemm_mfma(
        const bf16_t* __restrict__ A, const bf16_t* __restrict__ Wb,
        const float* __restrict__ bias, void* __restrict__ Cv,
        int N, int K, int M, int Kseg) {
    constexpr int BM = 128, BK = 64;
    __shared__ __align__(16) unsigned short lds[4 * 64 * 68];
    unsigned short* Als = lds;
    unsigned short* Bls = lds + BM * BK;

    int t = threadIdx.x;
    int lane = t & 63, wid = t >> 6;
    int quad = lane >> 4, l15 = lane & 15;
    int wave_m = wid & 1, wave_n = wid >> 1;
    int bm0 = blockIdx.y * BM;     // node tile
    int bn0 = blockIdx.x * BM;     // M tile (fastest-varying)
    int kbeg = SPLIT ? (int)blockIdx.z * Kseg : 0;
    int kend = SPLIT ? min(kbeg + Kseg, K) : K;

    f32x4 acc[4][4] = {};

    for (int k0 = kbeg; k0 < kend; k0 += BK) {
#pragma unroll
        for (int it = 0; it < 4; it++) {
            int idx = t + it * 256;
            int row = idx >> 3, c = idx & 7;
            int sw = ((c ^ (row & 7)) << 3);
            {
                int g = bm0 + row;
                short8 v = {};
                if (g < N) v = *(const short8*)(A + (size_t)g * K + k0 + c * 8);
                *(short8*)&Als[row * BK + sw] = v;
            }
            {
                int g = bn0 + row;
                short8 v = {};
                if (g < M) v = *(const short8*)(Wb + (size_t)g * K + k0 + c * 8);
                *(short8*)&Bls[row * BK + sw] = v;
            }
        }
        __syncthreads();

#pragma unroll
        for (int ks = 0; ks < 2; ks++) {
            short8 af[4], bfr[4];
            int ck = ks * 4 + quad;
            int sw = (ck ^ (l15 & 7)) << 3;
#pragma unroll
            for (int mt = 0; mt < 4; mt++)
                af[mt] = *(const short8*)&Als[(wave_m * 64 + mt * 16 + l15) * BK + sw];
#pragma unroll
            for (int nt = 0; nt < 4; nt++)
                bfr[nt] = *(const short8*)&Bls[(wave_n * 64 + nt * 16 + l15) * BK + sw];
#pragma unroll
            for (int mt = 0; mt < 4; mt++)
#pragma unroll
                for (int nt = 0; nt < 4; nt++)
                    acc[mt][nt] = __builtin_amdgcn_mfma_f32_16x16x32_bf16(
                        af[mt], bfr[nt], acc[mt][nt], 0, 0, 0);
        }
        __syncthreads();
    }

    if (!SPLIT && CBF) {
        // ---- coalesced epilogue: per-wave 64x64 patch through LDS ----
        constexpr int TST = 68;
        unsigned short* tw = lds + wid * 64 * TST;
#pragma unroll
        for (int mt = 0; mt < 4; mt++) {
#pragma unroll
            for (int nt = 0; nt < 4; nt++) {
                int tcol = nt * 16 + l15;
                float bv = BIAS ? bias[bn0 + wave_n * 64 + tcol] : 0.f;
#pragma unroll
                for (int r = 0; r < 4; r++) {
                    float x = acc[mt][nt][r];
                    if (BIAS) x += bv;
                    if (ACT == 1) x = x > 0.f ? x : 0.1f * x;
                    tw[(mt * 16 + quad * 4 + r) * TST + tcol] = f2bf(x);
                }
            }
        }
        __syncthreads();
        bf16_t* C = (bf16_t*)Cv;
        int lrow0 = lane >> 3, lcol = (lane & 7) * 8;
#pragma unroll
        for (int it = 0; it < 8; it++) {
            int lrow = it * 8 + lrow0;
            int row = bm0 + wave_m * 64 + lrow;
            if (row < N) {
                u16x8 v = *(const u16x8*)&tw[lrow * TST + lcol];
                *(u16x8*)&C[(size_t)row * M + bn0 + wave_n * 64 + lcol] = v;
            }
        }
    } else {
        float* Pz = SPLIT ? ((float*)Cv + (size_t)blockIdx.z * N * M) : (float*)Cv;
#pragma unroll
        for (int mt = 0; mt < 4; mt++) {
            int rbase = bm0 + wave_m * 64 + mt * 16 + quad * 4;
#pragma unroll
            for (int nt = 0; nt < 4; nt++) {
                int col = bn0 + wave_n * 64 + nt * 16 + l15;
                float bv = (BIAS && !SPLIT) ? bias[col] : 0.f;
#pragma unroll
                for (int r = 0; r < 4; r++) {
                    int row = rbase + r;
                    if (row >= N) continue;
                    float x = acc[mt][nt][r];
                    if (!SPLIT) {
                        if (BIAS) x += bv;
                        if (ACT == 1) x = x > 0.f ? x : 0.1f * x;
                    }
                    Pz[(size_t)row * M + col] = x;
                }
            }
        }
    }
}

// ---------------- split-K reduce + bias + leaky-relu (MLP1) ----------------

template <int S, bool CBF, int ACT>
__global__ __launch_bounds__(256) void k_red(
        const float* __restrict__ part, const float* __restrict__ bias,
        void* __restrict__ out, int GM, int Mmask) {
    int i = (blockIdx.x * 256 + threadIdx.x) * 4;
    if (i >= GM) return;
    float4 s = *(const float4*)&part[i];
#pragma unroll
    for (int z = 1; z < S; z++) {
        float4 p = *(const float4*)&part[(size_t)z * GM + i];
        s.x += p.x; s.y += p.y; s.z += p.z; s.w += p.w;
    }
    float4 b = *(const float4*)&bias[i & Mmask];
    float v[4] = {s.x + b.x, s.y + b.y, s.z + b.z, s.w + b.w};
#pragma unroll
    for (int j = 0; j < 4; j++)
        if (ACT == 1) v[j] = v[j] > 0.f ? v[j] : 0.1f * v[j];
    if (CBF) {
        u16x4 o = {f2bf(v[0]), f2bf(v[1]), f2bf(v[2]), f2bf(v[3])};
        *(u16x4*)((bf16_t*)out + i) = o;
    } else {
        float4 o; o.x = v[0]; o.y = v[1]; o.z = v[2]; o.w = v[3];
        *(float4*)((float*)out + i) = o;
    }
}

// ---------------- fused aggregation, sub-wave-per-node ----------------------

template <int F, bool BACT>
__global__ __launch_bounds__(256) void k_agg(
        const bf16_t* __restrict__ H, const int* __restrict__ rowptr,
        const int* __restrict__ csr, const float* __restrict__ dis,
        const float* __restrict__ bias, bf16_t* __restrict__ out, int N) {
    constexpr int SUB = F / 8;          // lanes per node
    constexpr int NPW = 64 / SUB;       // nodes per wave
    constexpr int SH  = (SUB == 16) ? 4 : 3;
    int gtid = blockIdx.x * 256 + threadIdx.x;
    int wave = gtid >> 6, lane = gtid & 63;
    int sub = lane >> SH, sl = lane & (SUB - 1);
    int node = wave * NPW + sub;
    if (node >= N) return;
    float di = dis[node];
    int s = rowptr[node], e = rowptr[node + 1];

    auto load_row = [&](const bf16_t* p, float (&r)[8]) {
        u16x8 v = *(const u16x8*)p;
#pragma unroll
        for (int f = 0; f < 8; f++) r[f] = bf2f(v[f]);
    };

    float acc[8], acc2[8];
    {
        float r[8];
        load_row(H + (size_t)node * F + sl * 8, r);
        float sln = di * di;   // self-loop norm = 1/deg
#pragma unroll
        for (int f = 0; f < 8; f++) { acc[f] = r[f] * sln; acc2[f] = 0.f; }
    }
    int p = s;
    for (; p + 2 <= e; p += 2) {
        int s0 = csr[p], s1 = csr[p + 1];
        float n0 = dis[s0] * di, n1 = dis[s1] * di;
        float r0[8], r1[8];
        load_row(H + (size_t)s0 * F + sl * 8, r0);
        load_row(H + (size_t)s1 * F + sl * 8, r1);
#pragma unroll
        for (int f = 0; f < 8; f++) { acc[f] += r0[f] * n0; acc2[f] += r1[f] * n1; }
    }
    if (p < e) {
        int s0 = csr[p];
        float n0 = dis[s0] * di;
        float r0[8];
        load_row(H + (size_t)s0 * F + sl * 8, r0);
#pragma unroll
        for (int f = 0; f < 8; f++) acc[f] += r0[f] * n0;
    }

    float o[8];
#pragma unroll
    for (int f = 0; f < 8; f++) {
        float v = acc[f] + acc2[f];
        if (BACT) {
            v += bias[sl * 8 + f];
            v = v > 0.f ? v : 0.1f * v;
        }
        o[f] = v;
    }
    u16x8 w = {f2bf(o[0]), f2bf(o[1]), f2bf(o[2]), f2bf(o[3]),
               f2bf(o[4]), f2bf(o[5]), f2bf(o[6]), f2bf(o[7])};
    *(u16x8*)(out + (size_t)node * F + sl * 8) = w;
}

// ---------------- fused MLP2-reduce + bias + lrelu + head ------------------

__global__ __launch_bounds__(256) void k_head2(
        const float* __restrict__ part, const float* __restrict__ L2b,
        const float* __restrict__ L3w, const float* __restrict__ L3b,
        float* __restrict__ out, int G) {
    int wv = (int)((blockIdx.x * blockDim.x + threadIdx.x) >> 6);
    int lane = threadIdx.x & 63;
    if (wv >= G) return;
    size_t base = (size_t)wv * 128 + lane * 2;
    size_t GM = (size_t)G * 128;
    float2 s = *(const float2*)&part[base];
#pragma unroll
    for (int z = 1; z < 4; z++) {
        float2 p = *(const float2*)&part[z * GM + base];
        s.x += p.x; s.y += p.y;
    }
    float2 b = *(const float2*)&L2b[lane * 2];
    float vx = s.x + b.x, vy = s.y + b.y;
    vx = vx > 0.f ? vx : 0.1f * vx;
    vy = vy > 0.f ? vy : 0.1f * vy;
    float2 wl = *(const float2*)&L3w[lane * 2];
    float d = vx * wl.x + vy * wl.y;
    for (int off = 32; off > 0; off >>= 1) d += __shfl_xor(d, off, 64);
    if (lane == 0) out[wv] = 1.f / (1.f + expf(-(d + L3b[0])));
}

// ---------------- launch ----------------

extern "C" void kernel_launch(void* const* d_in, const int* in_sizes, int n_in,
                              void* d_out, int out_size, void* d_ws, size_t ws_size,
                              hipStream_t stream) {
    const float* x   = (const float*)d_in[0];
    const int*   ei  = (const int*)d_in[1];
    const float* W1  = (const float*)d_in[2];  const float* b1  = (const float*)d_in[3];
    const float* W2  = (const float*)d_in[4];  const float* b2  = (const float*)d_in[5];
    const float* W3  = (const float*)d_in[6];  const float* b3  = (const float*)d_in[7];
    const float* L1w = (const float*)d_in[8];  const float* L1b = (const float*)d_in[9];
    const float* L2w = (const float*)d_in[10]; const float* L2b = (const float*)d_in[11];
    const float* L3w = (const float*)d_in[12]; const float* L3b = (const float*)d_in[13];
    float* out = (float*)d_out;

    const int C = 40;
    const int N = in_sizes[0] / C;     // 200000
    const int E = in_sizes[1] / 2;     // 1000000
    const int G = N / 40;              // 5000
    const int H1d = 128, H2d = 256, H3d = 128, M1 = 512, M2 = 128;
    const int K1 = 40 * H3d;           // 5120
    const int NB8 = CDIV(N, 8);        // nodes per dst bucket
    const int CAP = (E >> 3) + (E >> 6) + 256;   // per-bucket capacity

    // ---- workspace layout ----
    char* wsb = (char*)d_ws;
    size_t off = 0;
    auto alloc = [&](size_t bytes) -> void* {
        void* p = wsb + off;
        off += (bytes + 255) & ~(size_t)255;
        return p;
    };
    int*    flag   = (int*)alloc(4);
    int*    gcur   = (int*)alloc(4 * 8);
    int*    cnt    = (int*)alloc(4 * (size_t)(N + 1));
    int*    rowptr = (int*)alloc(4 * (size_t)(N + 1));
    int*    cur    = (int*)alloc(4 * (size_t)N);
    int*    csr    = (int*)alloc(4 * (size_t)E);
    int2*   temp   = (int2*)alloc(8 * 8 * (size_t)CAP);
    int*    bsum   = (int*)alloc(4 * 512);
    float*  dis    = (float*)alloc(4 * (size_t)N);
    bf16_t* Hb     = (bf16_t*)alloc(2 * (size_t)N * H2d);   // ping [N,256] bf16 (102.4 MB)
    bf16_t* Xb     = (bf16_t*)alloc(2 * (size_t)N * H2d);   // pong [N,256] bf16 (102.4 MB)
    bf16_t* g1b    = (bf16_t*)alloc(2 * (size_t)G * M1);
    bf16_t* W1b    = (bf16_t*)alloc(2 * (size_t)H1d * 64);
    bf16_t* W2b    = (bf16_t*)alloc(2 * (size_t)H2d * H1d);
    bf16_t* W3b    = (bf16_t*)alloc(2 * (size_t)H3d * H2d);
    bf16_t* L1wb   = (bf16_t*)alloc(2 * (size_t)M1 * K1);
    bf16_t* L2wb   = (bf16_t*)alloc(2 * (size_t)M2 * M1);
    if (off > ws_size) return;   // fail cleanly instead of faulting

    // aliasing (all within dead regions at time of use):
    bf16_t* xb   = Hb;            // [N,64]  pad(x)          — dead after agg1
    bf16_t* A1b  = Xb;            // [N,64]  agg(x)          — dead after GEMM1
    bf16_t* H1   = Hb;            // [N,128] lrelu(A1 W1+b1) — overwrites xb
    bf16_t* A2   = Xb;            // [N,128] agg(H1)         — overwrites A1b
    bf16_t* H2   = Hb;            // [N,256] lrelu(A2 W2+b2) — overwrites H1
    bf16_t* H3p  = Xb;            // [N,128] H2 W3           — overwrites A2
    bf16_t* X3   = Hb;            // [N,128] lrelu(agg(H3p)+b3) — overwrites H2
    float*  part = (float*)Xb;    // split-K partials (61.4 MB) — overwrites H3p

    // ---- weight pre-convert (fp32 -> bf16, K padded) ----
    WcSeg s0 = {W1,  W1b,  H1d, 40,  64,  H1d * 64 / 8};
    WcSeg s1 = {W2,  W2b,  H2d, H1d, H1d, H2d * H1d / 8};
    WcSeg s2 = {W3,  W3b,  H3d, H2d, H2d, H3d * H2d / 8};
    WcSeg s3 = {L1w, L1wb, M1,  K1,  K1,  M1 * K1 / 8};
    WcSeg s4 = {L2w, L2wb, M2,  M1,  M1,  M2 * M1 / 8};
    int wtotal = s0.nchunk + s1.nchunk + s2.nchunk + s3.nchunk + s4.nchunk;
    k_wconv<<<CDIV(wtotal, 256), 256, 0, stream>>>(s0, s1, s2, s3, s4, wtotal);

    // ---- CSR build: two-phase XCD-confined ----
    hipMemsetAsync(gcur, 0, sizeof(int) * 8, stream);
    hipMemsetAsync(cnt, 0, sizeof(int) * (size_t)(N + 1), stream);
    k_detect<<<1, 64, 0, stream>>>(ei, flag);
    k_binA<<<CDIV(E, 1024), 256, 0, stream>>>(ei, E, flag, NB8, CAP, gcur, temp, N);
    k_hist2<<<2048, 256, 0, stream>>>(temp, gcur, CAP, cnt);
    int nb = CDIV(N + 1, 1024);        // 196 <= 256
    k_blockred<<<nb, 256, 0, stream>>>(cnt, bsum, N + 1);
    k_scanpartials<<<1, 256, 0, stream>>>(bsum, nb);
    k_scanwrite<<<nb, 256, 0, stream>>>(cnt, bsum, rowptr, cur, dis, N + 1, N);
    k_fillB<<<2048, 256, 0, stream>>>(temp, gcur, CAP, cur, csr);

    const int NB = CDIV(N, 128);       // 1563
    const int GB = CDIV(G, 128);       // 40

    // ---- conv1 (aggregate-first in 40->64-dim) ----
    k_pad<<<CDIV(N * 64, 256), 256, 0, stream>>>(x, xb, N);
    k_agg<64, false><<<CDIV(N, 32), 256, 0, stream>>>(xb, rowptr, csr, dis, nullptr, A1b, N);
    gemm_mfma<true, true, 1, false><<<dim3(1, NB), 256, 0, stream>>>(A1b, W1b, b1, H1, N, 64, H1d, 0);
    // ---- conv2 (aggregate-first in 128-dim) ----
    k_agg<128, false><<<CDIV(N, 16), 256, 0, stream>>>(H1, rowptr, csr, dis, nullptr, A2, N);
    gemm_mfma<true, true, 1, false><<<dim3(2, NB), 256, 0, stream>>>(A2, W2b, b2, H2, N, H1d, H2d, 0);
    // ---- conv3 (transform-first: 256 -> 128, aggregate in 128-dim) ----
    gemm_mfma<true, false, 0, false><<<dim3(1, NB), 256, 0, stream>>>(H2, W3b, nullptr, H3p, N, H2d, H3d, 0);
    k_agg<128, true><<<CDIV(N, 16), 256, 0, stream>>>(H3p, rowptr, csr, dis, b3, X3, N);

    // ---- readout MLP1: split-K S=6 (960 blocks), Kseg=896 ----
    gemm_mfma<false, false, 0, true><<<dim3(M1 / 128, GB, 6), 256, 0, stream>>>(X3, L1wb, nullptr, part, G, K1, M1, 896);
    k_red<6, true, 1><<<CDIV(G * M1 / 4, 256), 256, 0, stream>>>(part, L1b, g1b, G * M1, M1 - 1);
    // ---- readout MLP2: split-K S=4 + fused reduce/head ----
    gemm_mfma<false, false, 0, true><<<dim3(1, GB, 4), 256, 0, stream>>>(g1b, L2wb, nullptr, part, G, M1, M2, M1 / 4);
    k_head2<<<CDIV(G, 4), 256, 0, stream>>>(part, L2b, L3w, L3b, out, G);
}